// Round 1
// baseline (533.304 us; speedup 1.0000x reference)
//
#include <hip/hip_runtime.h>

#define B_  2
#define S_  2048
#define D_  512
#define H_  8
#define E_  512
#define HE_ 4096

typedef _Float16 half8_t  __attribute__((ext_vector_type(8)));
typedef _Float16 half4_t  __attribute__((ext_vector_type(4)));
typedef float    floatx4  __attribute__((ext_vector_type(4)));
typedef __attribute__((address_space(1))) const unsigned int* gas_ptr;
typedef __attribute__((address_space(3))) unsigned int*       las_ptr;

// ---------------- fused cast fp32 -> fp16 for q,k,v ----------------
__global__ __launch_bounds__(256) void cast3_f16_kernel(
    const float* __restrict__ s0, const float* __restrict__ s1, const float* __restrict__ s2,
    _Float16* __restrict__ d0, _Float16* __restrict__ d1, _Float16* __restrict__ d2, int n4) {
    int i = blockIdx.x * 256 + threadIdx.x;
    if (i >= n4) return;
    const float* s = (blockIdx.y == 0) ? s0 : (blockIdx.y == 1) ? s1 : s2;
    _Float16*    d = (blockIdx.y == 0) ? d0 : (blockIdx.y == 1) ? d1 : d2;
    float4 v = ((const float4*)s)[i];
    half4_t h = { (_Float16)v.x, (_Float16)v.y, (_Float16)v.z, (_Float16)v.w };
    ((half4_t*)d)[i] = h;
}

// ------------- transpose + cast: 3 sources selected by z (Wq/Wk/Wv), each [H][R][C] ------
__global__ __launch_bounds__(256) void transpose3_cast_kernel(
    const float* __restrict__ p0, const float* __restrict__ p1, const float* __restrict__ p2,
    _Float16* __restrict__ q0, _Float16* __restrict__ q1, _Float16* __restrict__ q2,
    int R, int C) {
    __shared__ float t[32][33];
    int which = blockIdx.z >> 3, hh = blockIdx.z & 7;
    const float* src = ((which == 0) ? p0 : (which == 1) ? p1 : p2) + (long long)hh * R * C;
    _Float16*    dst = ((which == 0) ? q0 : (which == 1) ? q1 : q2) + (long long)hh * R * C;
    int c0 = blockIdx.x * 32, r0 = blockIdx.y * 32;
    int tx = threadIdx.x, ty = threadIdx.y;
#pragma unroll
    for (int i = 0; i < 32; i += 8)
        t[ty + i][tx] = src[(long long)(r0 + ty + i) * C + (c0 + tx)];
    __syncthreads();
#pragma unroll
    for (int i = 0; i < 32; i += 8)
        dst[(long long)(c0 + ty + i) * R + (r0 + tx)] = (_Float16)t[tx][ty + i];
}

__global__ __launch_bounds__(256) void transpose_cast_kernel(const float* __restrict__ src,
                                                             _Float16* __restrict__ dst,
                                                             int R, int C) {
    __shared__ float t[32][33];
    int c0 = blockIdx.x * 32, r0 = blockIdx.y * 32;
    int tx = threadIdx.x, ty = threadIdx.y;
#pragma unroll
    for (int i = 0; i < 32; i += 8)
        t[ty + i][tx] = src[(long long)(r0 + ty + i) * C + (c0 + tx)];
    __syncthreads();
#pragma unroll
    for (int i = 0; i < 32; i += 8)
        dst[(long long)(c0 + ty + i) * R + (r0 + tx)] = (_Float16)t[tx][ty + i];
}

// ===== shared swizzle notes (r9-validated, 0 bank conflicts) =====
// LDS rows are 32 halfs (64B) = 4 chunks of 16B. Store chunk = lin ^ ((row>>1)&3),
// achieved by pre-swizzling the GLOBAL source col: scg = ((lane&3)^((lane>>3)&3))*8
// (global_load_lds writes linearly: wave-uniform base + lane*16).
// Fragment read chunk: cra = (quad ^ ((l16>>1)&3))*8 undoes it.

// ------------- XCD-aware swizzle: pin gridDim.z/8 z-slices per XCD (T1) ----------
__device__ __forceinline__ void xcd_decode(int& z, int& by, int& bx) {
    int gx = gridDim.x, gy = gridDim.y, gz = gridDim.z;
    int bpz = gx * gy;
    int fid = blockIdx.x + gx * (blockIdx.y + gy * blockIdx.z);
    if ((gz & 7) == 0) {
        int xcd = fid & 7, sl = fid >> 3;
        int zg = gz >> 3;
        z = xcd * zg + sl / bpz;
        int inner = sl % bpz;
        by = inner / gx;
        bx = inner % gx;
    } else {
        z = blockIdx.z; by = blockIdx.y; bx = blockIdx.x;
    }
}

// ------------- merged QKV projection: z = which*16 + bb*8 + hh -------------
// Q,K -> flat [b,h,s,e]; V -> VT [b,h,e,s] with half4 stores down s.
__global__ __launch_bounds__(256) void gemm_qkv_kernel(
    const _Float16* __restrict__ Xq, const _Float16* __restrict__ Xk, const _Float16* __restrict__ Xv,
    const _Float16* __restrict__ WqT, const _Float16* __restrict__ WkT, const _Float16* __restrict__ WvT,
    const float* __restrict__ bq, const float* __restrict__ bk, const float* __restrict__ bv,
    _Float16* __restrict__ Qb, _Float16* __restrict__ Kb, _Float16* __restrict__ VT)
{
    int z, byy, bxx;
    xcd_decode(z, byy, bxx);
    int which = z >> 4, zz = z & 15;
    int bb = zz >> 3, hh = zz & 7;
    const _Float16* A  = ((which == 0) ? Xq : (which == 1) ? Xk : Xv) + (long long)bb * S_ * D_;
    const _Float16* Bt = ((which == 0) ? WqT : (which == 1) ? WkT : WvT) + (long long)hh * E_ * D_;
    const float* bias  = ((which == 0) ? bq : (which == 1) ? bk : bv) + hh * E_;

    int m0 = byy * 128;   // s
    int n0 = bxx * 128;   // e

    __shared__ __align__(16) _Float16 As[2][128][32];
    __shared__ __align__(16) _Float16 Bs[2][128][32];

    int tid  = threadIdx.x;
    int wave = tid >> 6, lane = tid & 63;
    int quad = lane >> 4, l16 = lane & 15;
    int wy = (wave >> 1) * 64, wx = (wave & 1) * 64;
    int pw = wave & 1, rw = (wave >> 1) * 64;
    int sr = lane >> 2;
    int scg = ((lane & 3) ^ ((lane >> 3) & 3)) * 8;
    _Float16* lA0 = &As[pw][rw][0];
    _Float16* lB0 = &Bs[pw][rw][0];
    int cra = (quad ^ ((l16 >> 1) & 3)) * 8;

    floatx4 acc[4][4] = {};

    for (int k0 = 0; k0 < D_; k0 += 64) {
        if (k0) __syncthreads();
        const _Float16* gA = A + (long long)(m0 + rw + sr) * D_ + k0 + pw * 32 + scg;
        const _Float16* gB = Bt + (long long)(n0 + rw + sr) * D_ + k0 + pw * 32 + scg;
#pragma unroll
        for (int j = 0; j < 4; j++) {
            __builtin_amdgcn_global_load_lds((gas_ptr)(gA + (long long)(j * 16) * D_),
                                             (las_ptr)(lA0 + j * 512), 16, 0, 0);
            __builtin_amdgcn_global_load_lds((gas_ptr)(gB + (long long)(j * 16) * D_),
                                             (las_ptr)(lB0 + j * 512), 16, 0, 0);
        }
        __syncthreads();
#pragma unroll
        for (int kc = 0; kc < 2; kc++) {
            half8_t af[4], bf[4];
#pragma unroll
            for (int i = 0; i < 4; i++) {
                af[i] = *(const half8_t*)&As[kc][wy + i * 16 + l16][cra];
                bf[i] = *(const half8_t*)&Bs[kc][wx + i * 16 + l16][cra];
            }
#pragma unroll
            for (int mi = 0; mi < 4; mi++)
#pragma unroll
                for (int ni = 0; ni < 4; ni++)
                    acc[mi][ni] = __builtin_amdgcn_mfma_f32_16x16x32_f16(af[mi], bf[ni], acc[mi][ni], 0, 0, 0);
        }
    }

    if (which < 2) {
        _Float16* C = ((which == 0) ? Qb : Kb) + ((long long)(bb * H_ + hh)) * S_ * E_;
#pragma unroll
        for (int mi = 0; mi < 4; mi++)
#pragma unroll
            for (int ni = 0; ni < 4; ni++)
#pragma unroll
                for (int r = 0; r < 4; r++) {
                    int row = m0 + wy + mi * 16 + quad * 4 + r;
                    int col = n0 + wx + ni * 16 + l16;
                    C[(long long)row * E_ + col] = (_Float16)(acc[mi][ni][r] + bias[col]);
                }
    } else {
        _Float16* C = VT + ((long long)(bb * H_ + hh)) * E_ * S_;
#pragma unroll
        for (int mi = 0; mi < 4; mi++)
#pragma unroll
            for (int ni = 0; ni < 4; ni++) {
                int row = m0 + wy + mi * 16 + quad * 4;     // s, multiple of 4
                int col = n0 + wx + ni * 16 + l16;          // e
                float bcol = bias[col];
                half4_t h4 = { (_Float16)(acc[mi][ni][0] + bcol), (_Float16)(acc[mi][ni][1] + bcol),
                               (_Float16)(acc[mi][ni][2] + bcol), (_Float16)(acc[mi][ni][3] + bcol) };
                *(half4_t*)(C + (long long)col * S_ + row) = h4;   // VT[e][s..s+3]
            }
    }
}

// ------------- 256x256-tile bt-GEMM (scores, PV), counted-vmcnt 4-deep pipeline -------------
// 8 waves (2M x 4N), wave tile 128x64. K-tiles of BK=32 in 4 LDS buffers (128 KiB total).
// Stage(t+3) is issued while computing t; buffer (t+3)&3 held tile t-1, fully consumed
// before the last barrier -> race-free by construction. vmcnt(8) at each tile boundary
// leaves tiles t+2,t+3 in flight (T4: never drain to 0 in the main loop).
__global__ __launch_bounds__(512, 2) void gemm_bt256_kernel(
    const _Float16* __restrict__ A, const _Float16* __restrict__ Bt,
    _Float16* __restrict__ C,
    int K, int lda, int ldb,
    long long a_z, long long b_z, long long c_b, long long c_h, int c_rs, int hdiv)
{
    int z, byy, bxx;
    xcd_decode(z, byy, bxx);
    int bb = z / hdiv, hh = z % hdiv;
    A  += (long long)z * a_z;
    Bt += (long long)z * b_z;
    _Float16* Cz = C + bb * c_b + hh * c_h;

    int m0 = byy * 256;
    int n0 = bxx * 256;

    __shared__ __align__(16) _Float16 As[4][256][32];   // 64 KiB
    __shared__ __align__(16) _Float16 Bs[4][256][32];   // 64 KiB

    int tid  = threadIdx.x;
    int wave = tid >> 6, lane = tid & 63;
    int quad = lane >> 4, l16 = lane & 15;
    int wm128 = (wave >> 2) * 128;        // wave M range (one A half)
    int wn64  = (wave & 3) * 64;          // wave N range
    int wave16 = wave * 16;
    int sr = lane >> 2;
    int scg = ((lane & 3) ^ ((lane >> 3) & 3)) * 8;
    int cra = (quad ^ ((l16 >> 1) & 3)) * 8;

    // stage K-tile t into buffer t&3: 4 global_load_lds per thread (2 A-halves + 2 B-halves)
    auto STAGE = [&](int t) {
        int buf = t & 3;
        int kk = t << 5;
        const _Float16* gA = A + (long long)(m0 + wave16 + sr) * lda + kk + scg;
        const _Float16* gB = Bt + (long long)(n0 + wave16 + sr) * ldb + kk + scg;
        _Float16* lA = &As[buf][wave16][0];
        _Float16* lB = &Bs[buf][wave16][0];
#pragma unroll
        for (int j = 0; j < 2; j++) {
            __builtin_amdgcn_global_load_lds((gas_ptr)(gA + (long long)(j * 128) * lda),
                                             (las_ptr)(lA + j * 128 * 32), 16, 0, 0);
            __builtin_amdgcn_global_load_lds((gas_ptr)(gB + (long long)(j * 128) * ldb),
                                             (las_ptr)(lB + j * 128 * 32), 16, 0, 0);
        }
    };

    int nt = K >> 5;     // uses here: 16 (scores) or 64 (PV); assumes nt >= 3

    STAGE(0);
    if (nt > 1) STAGE(1);
    if (nt > 2) STAGE(2);
    if (nt > 2)      asm volatile("s_waitcnt vmcnt(8)" ::: "memory");
    else if (nt > 1) asm volatile("s_waitcnt vmcnt(4)" ::: "memory");
    else             asm volatile("s_waitcnt vmcnt(0)" ::: "memory");
    __builtin_amdgcn_s_barrier();

    floatx4 acc[8][4] = {};

    for (int t = 0; t < nt; ++t) {
        if (t + 3 < nt) STAGE(t + 3);
        int buf = t & 3;
        half8_t af[8], bf[4];
#pragma unroll
        for (int i = 0; i < 8; i++)
            af[i] = *(const half8_t*)&As[buf][wm128 + i * 16 + l16][cra];
#pragma unroll
        for (int i = 0; i < 4; i++)
            bf[i] = *(const half8_t*)&Bs[buf][wn64 + i * 16 + l16][cra];
#pragma unroll
        for (int mi = 0; mi < 8; mi++)
#pragma unroll
            for (int ni = 0; ni < 4; ni++)
                acc[mi][ni] = __builtin_amdgcn_mfma_f32_16x16x32_f16(af[mi], bf[ni], acc[mi][ni], 0, 0, 0);
        if (t + 1 < nt) {
            // lgkmcnt(0): this wave's ds_reads complete before it crosses the barrier
            // (guards LDS reuse; MFMAs may sink past harmlessly).
            if (t + 3 < nt)      asm volatile("s_waitcnt vmcnt(8) lgkmcnt(0)" ::: "memory");
            else if (t + 2 < nt) asm volatile("s_waitcnt vmcnt(4) lgkmcnt(0)" ::: "memory");
            else                 asm volatile("s_waitcnt vmcnt(0) lgkmcnt(0)" ::: "memory");
            __builtin_amdgcn_s_barrier();
        }
    }

#pragma unroll
    for (int mi = 0; mi < 8; mi++)
#pragma unroll
        for (int ni = 0; ni < 4; ni++)
#pragma unroll
            for (int r = 0; r < 4; r++) {
                int row = m0 + wm128 + mi * 16 + quad * 4 + r;
                int col = n0 + wn64 + ni * 16 + l16;
                Cz[(long long)row * c_rs + col] = (_Float16)acc[mi][ni][r];
            }
}

// ------------- masked softmax, 8 heads per block (mask row reused via L1) -------------
__global__ __launch_bounds__(512) void softmax_mask8_kernel(_Float16* __restrict__ sc,
                                                            const int* __restrict__ mask)
{
    int b = blockIdx.z, s = blockIdx.x;
    int wave = threadIdx.x >> 6, lane = threadIdx.x & 63;
    _Float16* row = sc + ((long long)(b * H_ + wave) * S_ + s) * S_;
    const int* mrow = mask + ((long long)b * S_ + s) * S_;

    half8_t h[4];
    float v[32];
    float mx = -3.0e38f;
#pragma unroll
    for (int j = 0; j < 4; j++) {
        int c = j * 512 + lane * 8;
        h[j] = *(const half8_t*)(row + c);
        int4 mA = *(const int4*)(mrow + c);
        int4 mB = *(const int4*)(mrow + c + 4);
        int mm[8] = { mA.x, mA.y, mA.z, mA.w, mB.x, mB.y, mB.z, mB.w };
#pragma unroll
        for (int e = 0; e < 8; e++) {
            float val = mm[e] ? (float)h[j][e] : -1.0e9f;
            v[j * 8 + e] = val;
            mx = fmaxf(mx, val);
        }
    }
#pragma unroll
    for (int o = 32; o > 0; o >>= 1) mx = fmaxf(mx, __shfl_xor(mx, o));

    float sum = 0.0f;
#pragma unroll
    for (int i = 0; i < 32; i++) { v[i] = __expf(v[i] - mx); sum += v[i]; }
#pragma unroll
    for (int o = 32; o > 0; o >>= 1) sum += __shfl_xor(sum, o);

    float inv = 1.0f / sum;
#pragma unroll
    for (int j = 0; j < 4; j++) {
#pragma unroll
        for (int e = 0; e < 8; e++) h[j][e] = (_Float16)(v[j * 8 + e] * inv);
        *(half8_t*)(row + j * 512 + lane * 8) = h[j];
    }
}

// ------------- split-K bt-GEMM, 128(M)x64(N) tile, swizzled, fp32 atomic accumulate ------
__global__ __launch_bounds__(256) void gemm_bt_n64_splitk_kernel(
    const _Float16* __restrict__ A, const _Float16* __restrict__ Bt,
    const float* __restrict__ bias, float* __restrict__ C,
    int K, int lda, int ldb, int ldc, int ksplit)
{
    int m0 = blockIdx.y * 128;
    int n0 = blockIdx.x * 64;
    int kchunk = K / ksplit;
    int kbeg = blockIdx.z * kchunk;
    int kend = kbeg + kchunk;

    __shared__ __align__(16) _Float16 As[128][32];
    __shared__ __align__(16) _Float16 Bs[64][32];

    int tid  = threadIdx.x;
    int wave = tid >> 6, lane = tid & 63;
    int quad = lane >> 4, l16 = lane & 15;
    int wy = (wave >> 1) * 64, wx = (wave & 1) * 32;

    int srow = (wave << 4) + (lane >> 2);
    int scg = ((lane & 3) ^ ((lane >> 3) & 3)) * 8;
    _Float16* lA0 = &As[0][0] + (wave << 9);
    _Float16* lB0 = &Bs[0][0] + (wave << 9);
    int cra = (quad ^ ((l16 >> 1) & 3)) * 8;

    floatx4 acc[4][2] = {};

    for (int k0 = kbeg; k0 < kend; k0 += 32) {
        if (k0 != kbeg) __syncthreads();
        const _Float16* gA = A + (long long)(m0 + srow) * lda + k0 + scg;
        const _Float16* gB = Bt + (long long)(n0 + srow) * ldb + k0 + scg;
#pragma unroll
        for (int j = 0; j < 2; j++)
            __builtin_amdgcn_global_load_lds((gas_ptr)(gA + (long long)(j << 6) * lda),
                                             (las_ptr)(lA0 + (j << 11)), 16, 0, 0);
        __builtin_amdgcn_global_load_lds((gas_ptr)gB, (las_ptr)lB0, 16, 0, 0);
        __syncthreads();

        half8_t af[4], bf[2];
#pragma unroll
        for (int i = 0; i < 4; i++)
            af[i] = *(const half8_t*)&As[wy + i * 16 + l16][cra];
#pragma unroll
        for (int i = 0; i < 2; i++)
            bf[i] = *(const half8_t*)&Bs[wx + i * 16 + l16][cra];
#pragma unroll
        for (int mi = 0; mi < 4; mi++)
#pragma unroll
            for (int ni = 0; ni < 2; ni++)
                acc[mi][ni] = __builtin_amdgcn_mfma_f32_16x16x32_f16(af[mi], bf[ni], acc[mi][ni], 0, 0, 0);
    }

    int addb = (blockIdx.z == 0) && bias;
#pragma unroll
    for (int mi = 0; mi < 4; mi++)
#pragma unroll
        for (int ni = 0; ni < 2; ni++)
#pragma unroll
            for (int r = 0; r < 4; r++) {
                int row = m0 + wy + mi * 16 + quad * 4 + r;
                int col = n0 + wx + ni * 16 + l16;
                float v = acc[mi][ni][r];
                if (addb) v += bias[col];
                atomicAdd(&C[(long long)row * ldc + col], v);
            }
}

extern "C" void kernel_launch(void* const* d_in, const int* in_sizes, int n_in,
                              void* d_out, int out_size, void* d_ws, size_t ws_size,
                              hipStream_t stream)
{
    const float* qin = (const float*)d_in[0];
    const float* kin = (const float*)d_in[1];
    const float* vin = (const float*)d_in[2];
    const int*   mask = (const int*)d_in[3];
    const float* Wq = (const float*)d_in[4];
    const float* bq = (const float*)d_in[5];
    const float* Wk = (const float*)d_in[6];
    const float* bk = (const float*)d_in[7];
    const float* Wv = (const float*)d_in[8];
    const float* bv = (const float*)d_in[9];
    const float* Wo = (const float*)d_in[10];
    const float* bo = (const float*)d_in[11];
    float* out = (float*)d_out;

    char* ws = (char*)d_ws;
    size_t off = 0;
    _Float16* WoT = (_Float16*)(ws + off); off += (size_t)E_ * HE_ * 2;           // 4 MiB
    _Float16* Qb  = (_Float16*)(ws + off); off += (size_t)B_ * H_ * S_ * E_ * 2;  // 32 MiB
    _Float16* Kb  = (_Float16*)(ws + off); off += (size_t)B_ * H_ * S_ * E_ * 2;  // 32 MiB
    _Float16* VT  = (_Float16*)(ws + off); off += (size_t)B_ * H_ * E_ * S_ * 2;  // 32 MiB
    size_t region = off;
    _Float16* Xq  = (_Float16*)(ws + region);
    _Float16* Xk  = Xq  + (size_t)B_ * S_ * D_;
    _Float16* Xv  = Xk  + (size_t)B_ * S_ * D_;
    _Float16* WqT = Xv  + (size_t)B_ * S_ * D_;
    _Float16* WkT = WqT + (size_t)H_ * E_ * D_;
    _Float16* WvT = WkT + (size_t)H_ * E_ * D_;
    _Float16* SC  = (_Float16*)(ws + region);   // fp16 scores -> P (overlays dead scratch)
    _Float16* cat = Qb;                          // aliases Q (dead after scores GEMM)

    long long SE = (long long)S_ * E_;
    long long SS = (long long)S_ * S_;
    long long ES = (long long)E_ * S_;

    // zero d_out (split-K atomic accumulation target)
    (void)hipMemsetAsync(d_out, 0, (size_t)out_size * sizeof(float), stream);

    // 1) cast q,k,v to fp16
    int n4 = B_ * S_ * D_ / 4;
    cast3_f16_kernel<<<dim3(n4 / 256, 3), 256, 0, stream>>>(qin, kin, vin, Xq, Xk, Xv, n4);

    // 2) transpose+cast weights to Bt form
    dim3 tb(32, 8);
    transpose3_cast_kernel<<<dim3(E_ / 32, D_ / 32, 24), tb, 0, stream>>>(
        Wq, Wk, Wv, WqT, WkT, WvT, D_, E_);
    transpose_cast_kernel<<<dim3(E_ / 32, HE_ / 32, 1), tb, 0, stream>>>(Wo, WoT, HE_, E_);

    // 3) merged QKV projections: one dispatch, 48 z-slices (XCD-swizzled)
    gemm_qkv_kernel<<<dim3(E_ / 128, S_ / 128, 48), 256, 0, stream>>>(
        Xq, Xk, Xv, WqT, WkT, WvT, bq, bk, bv, Qb, Kb, VT);

    // 4a) raw scores [z][s][t] — 256x256 counted-vmcnt pipeline
    gemm_bt256_kernel<<<dim3(S_ / 256, S_ / 256, B_ * H_), 512, 0, stream>>>(
        Qb, Kb, SC, E_, E_, E_, SE, SE, 0, SS, S_, 32 /*hdiv>z: bb=0,hh=z*/);

    // 4b) masked softmax in place, 8 heads per block
    softmax_mask8_kernel<<<dim3(S_, 1, B_), 512, 0, stream>>>(SC, mask);

    // 4c) P @ V -> cat[b][s][h*E+e] — 256x256 counted-vmcnt pipeline
    gemm_bt256_kernel<<<dim3(E_ / 256, S_ / 256, B_ * H_), 512, 0, stream>>>(
        SC, VT, cat, S_, S_, S_, SS, ES, (long long)S_ * HE_, E_, HE_, H_);

    // 5) output projection: split-K (4) swizzled, atomic fp32 accumulate
    gemm_bt_n64_splitk_kernel<<<dim3(E_ / 64, (B_ * S_) / 128, 4), 256, 0, stream>>>(
        cat, WoT, bo, out, HE_, HE_, HE_, E_, 4);
}

// Round 2
// 519.046 us; speedup vs baseline: 1.0275x; 1.0275x over previous
//
#include <hip/hip_runtime.h>

#define B_  2
#define S_  2048
#define D_  512
#define H_  8
#define E_  512
#define HE_ 4096

typedef _Float16 half8_t  __attribute__((ext_vector_type(8)));
typedef _Float16 half4_t  __attribute__((ext_vector_type(4)));
typedef float    floatx4  __attribute__((ext_vector_type(4)));
typedef __attribute__((address_space(1))) const unsigned int* gas_ptr;
typedef __attribute__((address_space(3))) unsigned int*       las_ptr;

// ---------------- fused cast fp32 -> fp16 for q,k,v ----------------
__global__ __launch_bounds__(256) void cast3_f16_kernel(
    const float* __restrict__ s0, const float* __restrict__ s1, const float* __restrict__ s2,
    _Float16* __restrict__ d0, _Float16* __restrict__ d1, _Float16* __restrict__ d2, int n4) {
    int i = blockIdx.x * 256 + threadIdx.x;
    if (i >= n4) return;
    const float* s = (blockIdx.y == 0) ? s0 : (blockIdx.y == 1) ? s1 : s2;
    _Float16*    d = (blockIdx.y == 0) ? d0 : (blockIdx.y == 1) ? d1 : d2;
    float4 v = ((const float4*)s)[i];
    half4_t h = { (_Float16)v.x, (_Float16)v.y, (_Float16)v.z, (_Float16)v.w };
    ((half4_t*)d)[i] = h;
}

// ------------- transpose + cast: 3 sources selected by z (Wq/Wk/Wv), each [H][R][C] ------
__global__ __launch_bounds__(256) void transpose3_cast_kernel(
    const float* __restrict__ p0, const float* __restrict__ p1, const float* __restrict__ p2,
    _Float16* __restrict__ q0, _Float16* __restrict__ q1, _Float16* __restrict__ q2,
    int R, int C) {
    __shared__ float t[32][33];
    int which = blockIdx.z >> 3, hh = blockIdx.z & 7;
    const float* src = ((which == 0) ? p0 : (which == 1) ? p1 : p2) + (long long)hh * R * C;
    _Float16*    dst = ((which == 0) ? q0 : (which == 1) ? q1 : q2) + (long long)hh * R * C;
    int c0 = blockIdx.x * 32, r0 = blockIdx.y * 32;
    int tx = threadIdx.x, ty = threadIdx.y;
#pragma unroll
    for (int i = 0; i < 32; i += 8)
        t[ty + i][tx] = src[(long long)(r0 + ty + i) * C + (c0 + tx)];
    __syncthreads();
#pragma unroll
    for (int i = 0; i < 32; i += 8)
        dst[(long long)(c0 + ty + i) * R + (r0 + tx)] = (_Float16)t[tx][ty + i];
}

__global__ __launch_bounds__(256) void transpose_cast_kernel(const float* __restrict__ src,
                                                             _Float16* __restrict__ dst,
                                                             int R, int C) {
    __shared__ float t[32][33];
    int c0 = blockIdx.x * 32, r0 = blockIdx.y * 32;
    int tx = threadIdx.x, ty = threadIdx.y;
#pragma unroll
    for (int i = 0; i < 32; i += 8)
        t[ty + i][tx] = src[(long long)(r0 + ty + i) * C + (c0 + tx)];
    __syncthreads();
#pragma unroll
    for (int i = 0; i < 32; i += 8)
        dst[(long long)(c0 + ty + i) * R + (r0 + tx)] = (_Float16)t[tx][ty + i];
}

// ------------- XCD-aware swizzle: pin gridDim.z/8 z-slices per XCD (T1) ----------
__device__ __forceinline__ void xcd_decode(int& z, int& by, int& bx) {
    int gx = gridDim.x, gy = gridDim.y, gz = gridDim.z;
    int bpz = gx * gy;
    int fid = blockIdx.x + gx * (blockIdx.y + gy * blockIdx.z);
    if ((gz & 7) == 0) {
        int xcd = fid & 7, sl = fid >> 3;
        int zg = gz >> 3;
        z = xcd * zg + sl / bpz;
        int inner = sl % bpz;
        by = inner / gx;
        bx = inner % gx;
    } else {
        z = blockIdx.z; by = blockIdx.y; bx = blockIdx.x;
    }
}

// ===== 256x256 pipelined GEMM core (r2: register-ahead, the key fix) =====
// 8 waves (2M x 4N), wave tile 128x64. BK=32 K-tiles in a 4-buffer LDS ring (128 KiB).
// Per body t:
//   STAGE(t+3) -> buf[(t+3)&3]     (buf last read at body t-2, >=2 barriers ago: safe)
//   vmcnt(8); barrier              (ALL waves' tile-(t+1) stage loads have LANDED)
//   ds_read frags(t+1) -> next set (12 x b128; overlaps with...)
//   MFMA(t) from CURRENT reg set   (pure-reg cluster, setprio(1) around it: T5)
//   lgkmcnt(0); sched_barrier(0)   (rule #18 fence: next body's MFMA can't hoist)
// Frag sets are NAMED (fa0/fa1) and the loop hand-unrolled x2 (rule #20: no
// runtime-indexed reg arrays). vmcnt never drains to 0 in steady state (T4).
__device__ __forceinline__ void bt256_core(
    const _Float16* __restrict__ A, const _Float16* __restrict__ Bt,
    int lda, int ldb, int nt, int m0, int n0,
    _Float16 (*As)[256][32], _Float16 (*Bs)[256][32],
    floatx4 (&acc)[8][4])
{
    int tid  = threadIdx.x;
    int wave = tid >> 6, lane = tid & 63;
    int quad = lane >> 4, l16 = lane & 15;
    int wm128 = (wave >> 2) * 128;
    int wn64  = (wave & 3) * 64;
    int wave16 = wave * 16;
    int sr = lane >> 2;
    int scg = ((lane & 3) ^ ((lane >> 3) & 3)) * 8;   // pre-swizzled global chunk
    int cra = (quad ^ ((l16 >> 1) & 3)) * 8;          // fragment read chunk (undoes swizzle)

    const _Float16* gA0 = A + (long long)(m0 + wave16 + sr) * lda + scg;
    const _Float16* gB0 = Bt + (long long)(n0 + wave16 + sr) * ldb + scg;

    auto STAGE = [&](int t) {
        int buf = t & 3;
        const _Float16* gA = gA0 + (t << 5);
        const _Float16* gB = gB0 + (t << 5);
        _Float16* lA = &As[buf][wave16][0];
        _Float16* lB = &Bs[buf][wave16][0];
#pragma unroll
        for (int j = 0; j < 2; j++) {
            __builtin_amdgcn_global_load_lds((gas_ptr)(gA + (long long)(j * 128) * lda),
                                             (las_ptr)(lA + j * 128 * 32), 16, 0, 0);
            __builtin_amdgcn_global_load_lds((gas_ptr)(gB + (long long)(j * 128) * ldb),
                                             (las_ptr)(lB + j * 128 * 32), 16, 0, 0);
        }
    };
    auto DSREAD = [&](int t, half8_t (&fa)[8], half8_t (&fb)[4]) {
        int buf = t & 3;
#pragma unroll
        for (int i = 0; i < 8; i++)
            fa[i] = *(const half8_t*)&As[buf][wm128 + i * 16 + l16][cra];
#pragma unroll
        for (int i = 0; i < 4; i++)
            fb[i] = *(const half8_t*)&Bs[buf][wn64 + i * 16 + l16][cra];
    };
    auto MFMA = [&](half8_t (&fa)[8], half8_t (&fb)[4]) {
        __builtin_amdgcn_s_setprio(1);
#pragma unroll
        for (int mi = 0; mi < 8; mi++)
#pragma unroll
            for (int ni = 0; ni < 4; ni++)
                acc[mi][ni] = __builtin_amdgcn_mfma_f32_16x16x32_f16(fa[mi], fb[ni], acc[mi][ni], 0, 0, 0);
        __builtin_amdgcn_s_setprio(0);
    };
    auto BODY = [&](int t, half8_t (&ca)[8], half8_t (&cb)[4],
                    half8_t (&na)[8], half8_t (&nb)[4]) {
        if (t + 3 < nt) {
            STAGE(t + 3);
            asm volatile("s_waitcnt vmcnt(8)" ::: "memory");   // tile t+1 landed (mine)
            __builtin_amdgcn_s_barrier();                      // ... and everyone's
        } else if (t + 3 == nt) {
            asm volatile("s_waitcnt vmcnt(4)" ::: "memory");
            __builtin_amdgcn_s_barrier();
        } else if (t + 2 == nt) {
            asm volatile("s_waitcnt vmcnt(0)" ::: "memory");
            __builtin_amdgcn_s_barrier();
        }
        if (t + 1 < nt) DSREAD(t + 1, na, nb);
        MFMA(ca, cb);
        asm volatile("s_waitcnt lgkmcnt(0)" ::: "memory");
        __builtin_amdgcn_sched_barrier(0);
    };

    half8_t fa0[8], fb0[4], fa1[8], fb1[4];

    // prologue: 3 tiles in flight; compute tile 0's frags into set 0
    STAGE(0); STAGE(1); STAGE(2);
    asm volatile("s_waitcnt vmcnt(8)" ::: "memory");
    __builtin_amdgcn_s_barrier();
    DSREAD(0, fa0, fb0);
    asm volatile("s_waitcnt lgkmcnt(0)" ::: "memory");
    __builtin_amdgcn_sched_barrier(0);

    for (int t0 = 0; t0 < nt; t0 += 2) {
        BODY(t0,     fa0, fb0, fa1, fb1);
        BODY(t0 + 1, fa1, fb1, fa0, fb0);
    }
}

// ------------- generic 256-tile bt-GEMM (scores, PV) -------------
__global__ __launch_bounds__(512, 2) void gemm_bt256_kernel(
    const _Float16* __restrict__ A, const _Float16* __restrict__ Bt,
    _Float16* __restrict__ C,
    int K, int lda, int ldb,
    long long a_z, long long b_z, long long c_b, long long c_h, int c_rs, int hdiv)
{
    int z, byy, bxx;
    xcd_decode(z, byy, bxx);
    int bb = z / hdiv, hh = z % hdiv;
    A  += (long long)z * a_z;
    Bt += (long long)z * b_z;
    _Float16* Cz = C + bb * c_b + hh * c_h;

    int m0 = byy * 256;
    int n0 = bxx * 256;

    __shared__ __align__(16) _Float16 As[4][256][32];
    __shared__ __align__(16) _Float16 Bs[4][256][32];

    floatx4 acc[8][4] = {};
    bt256_core(A, Bt, lda, ldb, K >> 5, m0, n0, As, Bs, acc);

    int tid  = threadIdx.x;
    int wave = tid >> 6, lane = tid & 63;
    int quad = lane >> 4, l16 = lane & 15;
    int wm128 = (wave >> 2) * 128;
    int wn64  = (wave & 3) * 64;
#pragma unroll
    for (int mi = 0; mi < 8; mi++)
#pragma unroll
        for (int ni = 0; ni < 4; ni++)
#pragma unroll
            for (int r = 0; r < 4; r++) {
                int row = m0 + wm128 + mi * 16 + quad * 4 + r;
                int col = n0 + wn64 + ni * 16 + l16;
                Cz[(long long)row * c_rs + col] = (_Float16)acc[mi][ni][r];
            }
}

// ------------- QKV projection on the same core: z = which*16 + bb*8 + hh -------------
__global__ __launch_bounds__(512, 2) void gemm_qkv256_kernel(
    const _Float16* __restrict__ Xq, const _Float16* __restrict__ Xk, const _Float16* __restrict__ Xv,
    const _Float16* __restrict__ WqT, const _Float16* __restrict__ WkT, const _Float16* __restrict__ WvT,
    const float* __restrict__ bq, const float* __restrict__ bk, const float* __restrict__ bv,
    _Float16* __restrict__ Qb, _Float16* __restrict__ Kb, _Float16* __restrict__ VT)
{
    int z, byy, bxx;
    xcd_decode(z, byy, bxx);
    int which = z >> 4, zz = z & 15;
    int bb = zz >> 3, hh = zz & 7;
    const _Float16* A  = ((which == 0) ? Xq : (which == 1) ? Xk : Xv) + (long long)bb * S_ * D_;
    const _Float16* Bt = ((which == 0) ? WqT : (which == 1) ? WkT : WvT) + (long long)hh * E_ * D_;
    const float* bias  = ((which == 0) ? bq : (which == 1) ? bk : bv) + hh * E_;

    int m0 = byy * 256;   // s
    int n0 = bxx * 256;   // e

    __shared__ __align__(16) _Float16 As[4][256][32];
    __shared__ __align__(16) _Float16 Bs[4][256][32];

    floatx4 acc[8][4] = {};
    bt256_core(A, Bt, D_, D_, D_ / 32, m0, n0, As, Bs, acc);

    int tid  = threadIdx.x;
    int wave = tid >> 6, lane = tid & 63;
    int quad = lane >> 4, l16 = lane & 15;
    int wm128 = (wave >> 2) * 128;
    int wn64  = (wave & 3) * 64;

    if (which < 2) {
        _Float16* C = ((which == 0) ? Qb : Kb) + ((long long)(bb * H_ + hh)) * S_ * E_;
#pragma unroll
        for (int mi = 0; mi < 8; mi++)
#pragma unroll
            for (int ni = 0; ni < 4; ni++)
#pragma unroll
                for (int r = 0; r < 4; r++) {
                    int row = m0 + wm128 + mi * 16 + quad * 4 + r;
                    int col = n0 + wn64 + ni * 16 + l16;
                    C[(long long)row * E_ + col] = (_Float16)(acc[mi][ni][r] + bias[col]);
                }
    } else {
        _Float16* C = VT + ((long long)(bb * H_ + hh)) * E_ * S_;
#pragma unroll
        for (int mi = 0; mi < 8; mi++)
#pragma unroll
            for (int ni = 0; ni < 4; ni++) {
                int row = m0 + wm128 + mi * 16 + quad * 4;   // s, multiple of 4
                int col = n0 + wn64 + ni * 16 + l16;         // e
                float bcol = bias[col];
                half4_t h4 = { (_Float16)(acc[mi][ni][0] + bcol), (_Float16)(acc[mi][ni][1] + bcol),
                               (_Float16)(acc[mi][ni][2] + bcol), (_Float16)(acc[mi][ni][3] + bcol) };
                *(half4_t*)(C + (long long)col * S_ + row) = h4;   // VT[e][s..s+3]
            }
    }
}

// ------------- masked softmax, 8 heads per block (mask row reused via L1) -------------
__global__ __launch_bounds__(512) void softmax_mask8_kernel(_Float16* __restrict__ sc,
                                                            const int* __restrict__ mask)
{
    int b = blockIdx.z, s = blockIdx.x;
    int wave = threadIdx.x >> 6, lane = threadIdx.x & 63;
    _Float16* row = sc + ((long long)(b * H_ + wave) * S_ + s) * S_;
    const int* mrow = mask + ((long long)b * S_ + s) * S_;

    half8_t h[4];
    float v[32];
    float mx = -3.0e38f;
#pragma unroll
    for (int j = 0; j < 4; j++) {
        int c = j * 512 + lane * 8;
        h[j] = *(const half8_t*)(row + c);
        int4 mA = *(const int4*)(mrow + c);
        int4 mB = *(const int4*)(mrow + c + 4);
        int mm[8] = { mA.x, mA.y, mA.z, mA.w, mB.x, mB.y, mB.z, mB.w };
#pragma unroll
        for (int e = 0; e < 8; e++) {
            float val = mm[e] ? (float)h[j][e] : -1.0e9f;
            v[j * 8 + e] = val;
            mx = fmaxf(mx, val);
        }
    }
#pragma unroll
    for (int o = 32; o > 0; o >>= 1) mx = fmaxf(mx, __shfl_xor(mx, o));

    float sum = 0.0f;
#pragma unroll
    for (int i = 0; i < 32; i++) { v[i] = __expf(v[i] - mx); sum += v[i]; }
#pragma unroll
    for (int o = 32; o > 0; o >>= 1) sum += __shfl_xor(sum, o);

    float inv = 1.0f / sum;
#pragma unroll
    for (int j = 0; j < 4; j++) {
#pragma unroll
        for (int e = 0; e < 8; e++) h[j][e] = (_Float16)(v[j * 8 + e] * inv);
        *(half8_t*)(row + j * 512 + lane * 8) = h[j];
    }
}

// ------------- split-K bt-GEMM, 128(M)x64(N) tile, swizzled, fp32 atomic accumulate ------
__global__ __launch_bounds__(256) void gemm_bt_n64_splitk_kernel(
    const _Float16* __restrict__ A, const _Float16* __restrict__ Bt,
    const float* __restrict__ bias, float* __restrict__ C,
    int K, int lda, int ldb, int ldc, int ksplit)
{
    int m0 = blockIdx.y * 128;
    int n0 = blockIdx.x * 64;
    int kchunk = K / ksplit;
    int kbeg = blockIdx.z * kchunk;
    int kend = kbeg + kchunk;

    __shared__ __align__(16) _Float16 As[128][32];
    __shared__ __align__(16) _Float16 Bs[64][32];

    int tid  = threadIdx.x;
    int wave = tid >> 6, lane = tid & 63;
    int quad = lane >> 4, l16 = lane & 15;
    int wy = (wave >> 1) * 64, wx = (wave & 1) * 32;

    int srow = (wave << 4) + (lane >> 2);
    int scg = ((lane & 3) ^ ((lane >> 3) & 3)) * 8;
    _Float16* lA0 = &As[0][0] + (wave << 9);
    _Float16* lB0 = &Bs[0][0] + (wave << 9);
    int cra = (quad ^ ((l16 >> 1) & 3)) * 8;

    floatx4 acc[4][2] = {};

    for (int k0 = kbeg; k0 < kend; k0 += 32) {
        if (k0 != kbeg) __syncthreads();
        const _Float16* gA = A + (long long)(m0 + srow) * lda + k0 + scg;
        const _Float16* gB = Bt + (long long)(n0 + srow) * ldb + k0 + scg;
#pragma unroll
        for (int j = 0; j < 2; j++)
            __builtin_amdgcn_global_load_lds((gas_ptr)(gA + (long long)(j << 6) * lda),
                                             (las_ptr)(lA0 + (j << 11)), 16, 0, 0);
        __builtin_amdgcn_global_load_lds((gas_ptr)gB, (las_ptr)lB0, 16, 0, 0);
        __syncthreads();

        half8_t af[4], bf[2];
#pragma unroll
        for (int i = 0; i < 4; i++)
            af[i] = *(const half8_t*)&As[wy + i * 16 + l16][cra];
#pragma unroll
        for (int i = 0; i < 2; i++)
            bf[i] = *(const half8_t*)&Bs[wx + i * 16 + l16][cra];
#pragma unroll
        for (int mi = 0; mi < 4; mi++)
#pragma unroll
            for (int ni = 0; ni < 2; ni++)
                acc[mi][ni] = __builtin_amdgcn_mfma_f32_16x16x32_f16(af[mi], bf[ni], acc[mi][ni], 0, 0, 0);
    }

    int addb = (blockIdx.z == 0) && bias;
#pragma unroll
    for (int mi = 0; mi < 4; mi++)
#pragma unroll
        for (int ni = 0; ni < 2; ni++)
#pragma unroll
            for (int r = 0; r < 4; r++) {
                int row = m0 + wy + mi * 16 + quad * 4 + r;
                int col = n0 + wx + ni * 16 + l16;
                float v = acc[mi][ni][r];
                if (addb) v += bias[col];
                atomicAdd(&C[(long long)row * ldc + col], v);
            }
}

extern "C" void kernel_launch(void* const* d_in, const int* in_sizes, int n_in,
                              void* d_out, int out_size, void* d_ws, size_t ws_size,
                              hipStream_t stream)
{
    const float* qin = (const float*)d_in[0];
    const float* kin = (const float*)d_in[1];
    const float* vin = (const float*)d_in[2];
    const int*   mask = (const int*)d_in[3];
    const float* Wq = (const float*)d_in[4];
    const float* bq = (const float*)d_in[5];
    const float* Wk = (const float*)d_in[6];
    const float* bk = (const float*)d_in[7];
    const float* Wv = (const float*)d_in[8];
    const float* bv = (const float*)d_in[9];
    const float* Wo = (const float*)d_in[10];
    const float* bo = (const float*)d_in[11];
    float* out = (float*)d_out;

    char* ws = (char*)d_ws;
    size_t off = 0;
    _Float16* WoT = (_Float16*)(ws + off); off += (size_t)E_ * HE_ * 2;           // 4 MiB
    _Float16* Qb  = (_Float16*)(ws + off); off += (size_t)B_ * H_ * S_ * E_ * 2;  // 32 MiB
    _Float16* Kb  = (_Float16*)(ws + off); off += (size_t)B_ * H_ * S_ * E_ * 2;  // 32 MiB
    _Float16* VT  = (_Float16*)(ws + off); off += (size_t)B_ * H_ * E_ * S_ * 2;  // 32 MiB
    size_t region = off;
    _Float16* Xq  = (_Float16*)(ws + region);
    _Float16* Xk  = Xq  + (size_t)B_ * S_ * D_;
    _Float16* Xv  = Xk  + (size_t)B_ * S_ * D_;
    _Float16* WqT = Xv  + (size_t)B_ * S_ * D_;
    _Float16* WkT = WqT + (size_t)H_ * E_ * D_;
    _Float16* WvT = WkT + (size_t)H_ * E_ * D_;
    _Float16* SC  = (_Float16*)(ws + region);   // fp16 scores -> P (overlays dead scratch)
    _Float16* cat = Qb;                          // aliases Q (dead after scores GEMM)

    long long SE = (long long)S_ * E_;
    long long SS = (long long)S_ * S_;
    long long ES = (long long)E_ * S_;

    // zero d_out (split-K atomic accumulation target)
    (void)hipMemsetAsync(d_out, 0, (size_t)out_size * sizeof(float), stream);

    // 1) cast q,k,v to fp16
    int n4 = B_ * S_ * D_ / 4;
    cast3_f16_kernel<<<dim3(n4 / 256, 3), 256, 0, stream>>>(qin, kin, vin, Xq, Xk, Xv, n4);

    // 2) transpose+cast weights to Bt form
    dim3 tb(32, 8);
    transpose3_cast_kernel<<<dim3(E_ / 32, D_ / 32, 24), tb, 0, stream>>>(
        Wq, Wk, Wv, WqT, WkT, WvT, D_, E_);
    transpose_cast_kernel<<<dim3(E_ / 32, HE_ / 32, 1), tb, 0, stream>>>(Wo, WoT, HE_, E_);

    // 3) merged QKV projections on the pipelined 256^2 core (48 z-slices, XCD-swizzled)
    gemm_qkv256_kernel<<<dim3(E_ / 256, S_ / 256, 48), 512, 0, stream>>>(
        Xq, Xk, Xv, WqT, WkT, WvT, bq, bk, bv, Qb, Kb, VT);

    // 4a) raw scores [z][s][t]
    gemm_bt256_kernel<<<dim3(S_ / 256, S_ / 256, B_ * H_), 512, 0, stream>>>(
        Qb, Kb, SC, E_, E_, E_, SE, SE, 0, SS, S_, 32 /*hdiv>z: bb=0,hh=z*/);

    // 4b) masked softmax in place, 8 heads per block
    softmax_mask8_kernel<<<dim3(S_, 1, B_), 512, 0, stream>>>(SC, mask);

    // 4c) P @ V -> cat[b][s][h*E+e]
    gemm_bt256_kernel<<<dim3(E_ / 256, S_ / 256, B_ * H_), 512, 0, stream>>>(
        SC, VT, cat, S_, S_, S_, SS, ES, (long long)S_ * HE_, E_, HE_, H_);

    // 5) output projection: split-K (4) swizzled, atomic fp32 accumulate
    gemm_bt_n64_splitk_kernel<<<dim3(E_ / 64, (B_ * S_) / 128, 4), 256, 0, stream>>>(
        cat, WoT, bo, out, HE_, HE_, HE_, E_, 4);
}

// Round 3
// 487.818 us; speedup vs baseline: 1.0932x; 1.0640x over previous
//
#include <hip/hip_runtime.h>

#define B_  2
#define S_  2048
#define D_  512
#define H_  8
#define E_  512
#define HE_ 4096

typedef _Float16 half8_t  __attribute__((ext_vector_type(8)));
typedef _Float16 half4_t  __attribute__((ext_vector_type(4)));
typedef float    floatx4  __attribute__((ext_vector_type(4)));
typedef __attribute__((address_space(1))) const unsigned int* gas_ptr;
typedef __attribute__((address_space(3))) unsigned int*       las_ptr;

// ---------------- fused cast fp32 -> fp16 for q,k,v ----------------
__global__ __launch_bounds__(256) void cast3_f16_kernel(
    const float* __restrict__ s0, const float* __restrict__ s1, const float* __restrict__ s2,
    _Float16* __restrict__ d0, _Float16* __restrict__ d1, _Float16* __restrict__ d2, int n4) {
    int i = blockIdx.x * 256 + threadIdx.x;
    if (i >= n4) return;
    const float* s = (blockIdx.y == 0) ? s0 : (blockIdx.y == 1) ? s1 : s2;
    _Float16*    d = (blockIdx.y == 0) ? d0 : (blockIdx.y == 1) ? d1 : d2;
    float4 v = ((const float4*)s)[i];
    half4_t h = { (_Float16)v.x, (_Float16)v.y, (_Float16)v.z, (_Float16)v.w };
    ((half4_t*)d)[i] = h;
}

// ------------- transpose + cast: 3 sources selected by z (Wq/Wk/Wv), each [H][R][C] ------
__global__ __launch_bounds__(256) void transpose3_cast_kernel(
    const float* __restrict__ p0, const float* __restrict__ p1, const float* __restrict__ p2,
    _Float16* __restrict__ q0, _Float16* __restrict__ q1, _Float16* __restrict__ q2,
    int R, int C) {
    __shared__ float t[32][33];
    int which = blockIdx.z >> 3, hh = blockIdx.z & 7;
    const float* src = ((which == 0) ? p0 : (which == 1) ? p1 : p2) + (long long)hh * R * C;
    _Float16*    dst = ((which == 0) ? q0 : (which == 1) ? q1 : q2) + (long long)hh * R * C;
    int c0 = blockIdx.x * 32, r0 = blockIdx.y * 32;
    int tx = threadIdx.x, ty = threadIdx.y;
#pragma unroll
    for (int i = 0; i < 32; i += 8)
        t[ty + i][tx] = src[(long long)(r0 + ty + i) * C + (c0 + tx)];
    __syncthreads();
#pragma unroll
    for (int i = 0; i < 32; i += 8)
        dst[(long long)(c0 + ty + i) * R + (r0 + tx)] = (_Float16)t[tx][ty + i];
}

__global__ __launch_bounds__(256) void transpose_cast_kernel(const float* __restrict__ src,
                                                             _Float16* __restrict__ dst,
                                                             int R, int C) {
    __shared__ float t[32][33];
    int c0 = blockIdx.x * 32, r0 = blockIdx.y * 32;
    int tx = threadIdx.x, ty = threadIdx.y;
#pragma unroll
    for (int i = 0; i < 32; i += 8)
        t[ty + i][tx] = src[(long long)(r0 + ty + i) * C + (c0 + tx)];
    __syncthreads();
#pragma unroll
    for (int i = 0; i < 32; i += 8)
        dst[(long long)(c0 + ty + i) * R + (r0 + tx)] = (_Float16)t[tx][ty + i];
}

// ------------- XCD-aware swizzle: pin gridDim.z/8 z-slices per XCD (T1) ----------
__device__ __forceinline__ void xcd_decode(int& z, int& by, int& bx) {
    int gx = gridDim.x, gy = gridDim.y, gz = gridDim.z;
    int bpz = gx * gy;
    int fid = blockIdx.x + gx * (blockIdx.y + gy * blockIdx.z);
    if ((gz & 7) == 0) {
        int xcd = fid & 7, sl = fid >> 3;
        int zg = gz >> 3;
        z = xcd * zg + sl / bpz;
        int inner = sl % bpz;
        by = inner / gx;
        bx = inner % gx;
    } else {
        z = blockIdx.z; by = blockIdx.y; bx = blockIdx.x;
    }
}

// ===== 256x256 GEMM core, m201-style phase schedule (r3) =====
// 8 waves (2M x 4N), wave tile 128x64. BK=32 K-tiles in a 4-slot LDS ring (128 KiB).
// Per tile t, TWO phases (4 barriers/tile, matching m201's 2-barriers-per-phase):
//  alpha: { rd faL(t)[4] + fb(t)[4]; STAGE_A(t+3)[2 gload_lds]; bar;
//           lgkm(0)+schedbar; prio1; 16 MFMA (mi 0-3); prio0; bar }
//  beta:  { rd faH(t)[4]; STAGE_B(t+3)[2]; vmcnt(8|4|0); bar;
//           lgkm(0)+schedbar; prio1; 16 MFMA (mi 4-7); prio0; bar }
// Reads are issued BEFORE the mid barrier so the LDS pipe drains them during the
// barrier wait / other waves' MFMA windows (small paced clumps, not 12-deep bursts).
// vmcnt is per-wave but sits BEFORE a barrier: after the barrier, ALL waves'
// tile-(t+1) stages have landed -> alpha(t+1) reads are safe collectively.
// Overwrite safety: STAGE_A(t+3) rewrites A-slot (t-1)&3; the last reads of A(t-1)
// (faH at beta(t-1)) completed at beta(t-1)'s lgkm(0), before its barriers. Same
// for STAGE_B vs fb(t-1) read at alpha(t-1). vmcnt never drains in steady state.
__device__ __forceinline__ void bt256_core(
    const _Float16* __restrict__ A, const _Float16* __restrict__ Bt,
    int lda, int ldb, int nt, int m0, int n0,
    _Float16 (*As)[256][32], _Float16 (*Bs)[256][32],
    floatx4 (&acc)[8][4])
{
    int tid  = threadIdx.x;
    int wave = tid >> 6, lane = tid & 63;
    int quad = lane >> 4, l16 = lane & 15;
    int wm128 = (wave >> 2) * 128;
    int wn64  = (wave & 3) * 64;
    int wave16 = wave * 16;
    int sr = lane >> 2;
    int scg = ((lane & 3) ^ ((lane >> 3) & 3)) * 8;   // pre-swizzled global chunk
    int cra = (quad ^ ((l16 >> 1) & 3)) * 8;          // fragment read chunk (undoes swizzle)

    const _Float16* gA0 = A + (long long)(m0 + wave16 + sr) * lda + scg;
    const _Float16* gB0 = Bt + (long long)(n0 + wave16 + sr) * ldb + scg;

    auto STAGE_A = [&](int t) {
        int buf = t & 3;
        const _Float16* gA = gA0 + (t << 5);
        _Float16* lA = &As[buf][wave16][0];
#pragma unroll
        for (int j = 0; j < 2; j++)
            __builtin_amdgcn_global_load_lds((gas_ptr)(gA + (long long)(j * 128) * lda),
                                             (las_ptr)(lA + j * 128 * 32), 16, 0, 0);
    };
    auto STAGE_B = [&](int t) {
        int buf = t & 3;
        const _Float16* gB = gB0 + (t << 5);
        _Float16* lB = &Bs[buf][wave16][0];
#pragma unroll
        for (int j = 0; j < 2; j++)
            __builtin_amdgcn_global_load_lds((gas_ptr)(gB + (long long)(j * 128) * ldb),
                                             (las_ptr)(lB + j * 128 * 32), 16, 0, 0);
    };
    auto RD_A = [&](int t, int h, half8_t (&fa)[4]) {    // A frags mi = h*4 .. h*4+3
        int buf = t & 3;
#pragma unroll
        for (int i = 0; i < 4; i++)
            fa[i] = *(const half8_t*)&As[buf][wm128 + (h * 4 + i) * 16 + l16][cra];
    };
    auto RD_B = [&](int t, half8_t (&fb)[4]) {
        int buf = t & 3;
#pragma unroll
        for (int i = 0; i < 4; i++)
            fb[i] = *(const half8_t*)&Bs[buf][wn64 + i * 16 + l16][cra];
    };
    auto MFMA16 = [&](int h, half8_t (&fa)[4], half8_t (&fb)[4]) {
        __builtin_amdgcn_s_setprio(1);
#pragma unroll
        for (int mi = 0; mi < 4; mi++)
#pragma unroll
            for (int ni = 0; ni < 4; ni++)
                acc[h * 4 + mi][ni] =
                    __builtin_amdgcn_mfma_f32_16x16x32_f16(fa[mi], fb[ni], acc[h * 4 + mi][ni], 0, 0, 0);
        __builtin_amdgcn_s_setprio(0);
    };

    // prologue: stage tiles 0,1,2 (12 loads/thread); wait tile 0 (leave 8)
    STAGE_A(0); STAGE_B(0); STAGE_A(1); STAGE_B(1); STAGE_A(2); STAGE_B(2);
    asm volatile("s_waitcnt vmcnt(8)" ::: "memory");
    __builtin_amdgcn_s_barrier();

    half8_t faL[4], faH[4], fb[4];

    for (int t = 0; t < nt; ++t) {
        // ---------- phase alpha ----------
        RD_A(t, 0, faL);
        RD_B(t, fb);
        if (t + 3 < nt) STAGE_A(t + 3);
        __builtin_amdgcn_sched_barrier(0);
        __builtin_amdgcn_s_barrier();
        asm volatile("s_waitcnt lgkmcnt(0)" ::: "memory");
        __builtin_amdgcn_sched_barrier(0);
        MFMA16(0, faL, fb);
        __builtin_amdgcn_s_barrier();

        // ---------- phase beta ----------
        RD_A(t, 1, faH);
        if (t + 3 < nt) STAGE_B(t + 3);
        // collective guarantee for tile t+1 before alpha(t+1)'s reads:
        if (t + 1 < nt) {
            if (t + 3 < nt)       asm volatile("s_waitcnt vmcnt(8)" ::: "memory");
            else if (t + 3 == nt) asm volatile("s_waitcnt vmcnt(4)" ::: "memory");
            else                  asm volatile("s_waitcnt vmcnt(0)" ::: "memory");
        }
        __builtin_amdgcn_sched_barrier(0);
        __builtin_amdgcn_s_barrier();
        asm volatile("s_waitcnt lgkmcnt(0)" ::: "memory");
        __builtin_amdgcn_sched_barrier(0);
        MFMA16(1, faH, fb);
        __builtin_amdgcn_s_barrier();
    }
}

// ------------- generic 256-tile bt-GEMM (scores, PV) -------------
__global__ __launch_bounds__(512, 2) void gemm_bt256_kernel(
    const _Float16* __restrict__ A, const _Float16* __restrict__ Bt,
    _Float16* __restrict__ C,
    int K, int lda, int ldb,
    long long a_z, long long b_z, long long c_b, long long c_h, int c_rs, int hdiv)
{
    int z, byy, bxx;
    xcd_decode(z, byy, bxx);
    int bb = z / hdiv, hh = z % hdiv;
    A  += (long long)z * a_z;
    Bt += (long long)z * b_z;
    _Float16* Cz = C + bb * c_b + hh * c_h;

    int m0 = byy * 256;
    int n0 = bxx * 256;

    __shared__ __align__(16) _Float16 As[4][256][32];
    __shared__ __align__(16) _Float16 Bs[4][256][32];

    floatx4 acc[8][4] = {};
    bt256_core(A, Bt, lda, ldb, K >> 5, m0, n0, As, Bs, acc);

    int tid  = threadIdx.x;
    int wave = tid >> 6, lane = tid & 63;
    int quad = lane >> 4, l16 = lane & 15;
    int wm128 = (wave >> 2) * 128;
    int wn64  = (wave & 3) * 64;
#pragma unroll
    for (int mi = 0; mi < 8; mi++)
#pragma unroll
        for (int ni = 0; ni < 4; ni++)
#pragma unroll
            for (int r = 0; r < 4; r++) {
                int row = m0 + wm128 + mi * 16 + quad * 4 + r;
                int col = n0 + wn64 + ni * 16 + l16;
                Cz[(long long)row * c_rs + col] = (_Float16)acc[mi][ni][r];
            }
}

// ------------- QKV projection on the same core: z = which*16 + bb*8 + hh -------------
__global__ __launch_bounds__(512, 2) void gemm_qkv256_kernel(
    const _Float16* __restrict__ Xq, const _Float16* __restrict__ Xk, const _Float16* __restrict__ Xv,
    const _Float16* __restrict__ WqT, const _Float16* __restrict__ WkT, const _Float16* __restrict__ WvT,
    const float* __restrict__ bq, const float* __restrict__ bk, const float* __restrict__ bv,
    _Float16* __restrict__ Qb, _Float16* __restrict__ Kb, _Float16* __restrict__ VT)
{
    int z, byy, bxx;
    xcd_decode(z, byy, bxx);
    int which = z >> 4, zz = z & 15;
    int bb = zz >> 3, hh = zz & 7;
    const _Float16* A  = ((which == 0) ? Xq : (which == 1) ? Xk : Xv) + (long long)bb * S_ * D_;
    const _Float16* Bt = ((which == 0) ? WqT : (which == 1) ? WkT : WvT) + (long long)hh * E_ * D_;
    const float* bias  = ((which == 0) ? bq : (which == 1) ? bk : bv) + hh * E_;

    int m0 = byy * 256;   // s
    int n0 = bxx * 256;   // e

    __shared__ __align__(16) _Float16 As[4][256][32];
    __shared__ __align__(16) _Float16 Bs[4][256][32];

    floatx4 acc[8][4] = {};
    bt256_core(A, Bt, D_, D_, D_ / 32, m0, n0, As, Bs, acc);

    int tid  = threadIdx.x;
    int wave = tid >> 6, lane = tid & 63;
    int quad = lane >> 4, l16 = lane & 15;
    int wm128 = (wave >> 2) * 128;
    int wn64  = (wave & 3) * 64;

    if (which < 2) {
        _Float16* C = ((which == 0) ? Qb : Kb) + ((long long)(bb * H_ + hh)) * S_ * E_;
#pragma unroll
        for (int mi = 0; mi < 8; mi++)
#pragma unroll
            for (int ni = 0; ni < 4; ni++)
#pragma unroll
                for (int r = 0; r < 4; r++) {
                    int row = m0 + wm128 + mi * 16 + quad * 4 + r;
                    int col = n0 + wn64 + ni * 16 + l16;
                    C[(long long)row * E_ + col] = (_Float16)(acc[mi][ni][r] + bias[col]);
                }
    } else {
        _Float16* C = VT + ((long long)(bb * H_ + hh)) * E_ * S_;
#pragma unroll
        for (int mi = 0; mi < 8; mi++)
#pragma unroll
            for (int ni = 0; ni < 4; ni++) {
                int row = m0 + wm128 + mi * 16 + quad * 4;   // s, multiple of 4
                int col = n0 + wn64 + ni * 16 + l16;         // e
                float bcol = bias[col];
                half4_t h4 = { (_Float16)(acc[mi][ni][0] + bcol), (_Float16)(acc[mi][ni][1] + bcol),
                               (_Float16)(acc[mi][ni][2] + bcol), (_Float16)(acc[mi][ni][3] + bcol) };
                *(half4_t*)(C + (long long)col * S_ + row) = h4;   // VT[e][s..s+3]
            }
    }
}

// ------------- masked softmax, 8 heads per block (mask row reused via L1) -------------
__global__ __launch_bounds__(512) void softmax_mask8_kernel(_Float16* __restrict__ sc,
                                                            const int* __restrict__ mask)
{
    int b = blockIdx.z, s = blockIdx.x;
    int wave = threadIdx.x >> 6, lane = threadIdx.x & 63;
    _Float16* row = sc + ((long long)(b * H_ + wave) * S_ + s) * S_;
    const int* mrow = mask + ((long long)b * S_ + s) * S_;

    half8_t h[4];
    float v[32];
    float mx = -3.0e38f;
#pragma unroll
    for (int j = 0; j < 4; j++) {
        int c = j * 512 + lane * 8;
        h[j] = *(const half8_t*)(row + c);
        int4 mA = *(const int4*)(mrow + c);
        int4 mB = *(const int4*)(mrow + c + 4);
        int mm[8] = { mA.x, mA.y, mA.z, mA.w, mB.x, mB.y, mB.z, mB.w };
#pragma unroll
        for (int e = 0; e < 8; e++) {
            float val = mm[e] ? (float)h[j][e] : -1.0e9f;
            v[j * 8 + e] = val;
            mx = fmaxf(mx, val);
        }
    }
#pragma unroll
    for (int o = 32; o > 0; o >>= 1) mx = fmaxf(mx, __shfl_xor(mx, o));

    float sum = 0.0f;
#pragma unroll
    for (int i = 0; i < 32; i++) { v[i] = __expf(v[i] - mx); sum += v[i]; }
#pragma unroll
    for (int o = 32; o > 0; o >>= 1) sum += __shfl_xor(sum, o);

    float inv = 1.0f / sum;
#pragma unroll
    for (int j = 0; j < 4; j++) {
#pragma unroll
        for (int e = 0; e < 8; e++) h[j][e] = (_Float16)(v[j * 8 + e] * inv);
        *(half8_t*)(row + j * 512 + lane * 8) = h[j];
    }
}

// ------------- split-K bt-GEMM, 128(M)x64(N) tile, swizzled, fp32 atomic accumulate ------
__global__ __launch_bounds__(256) void gemm_bt_n64_splitk_kernel(
    const _Float16* __restrict__ A, const _Float16* __restrict__ Bt,
    const float* __restrict__ bias, float* __restrict__ C,
    int K, int lda, int ldb, int ldc, int ksplit)
{
    int m0 = blockIdx.y * 128;
    int n0 = blockIdx.x * 64;
    int kchunk = K / ksplit;
    int kbeg = blockIdx.z * kchunk;
    int kend = kbeg + kchunk;

    __shared__ __align__(16) _Float16 As[128][32];
    __shared__ __align__(16) _Float16 Bs[64][32];

    int tid  = threadIdx.x;
    int wave = tid >> 6, lane = tid & 63;
    int quad = lane >> 4, l16 = lane & 15;
    int wy = (wave >> 1) * 64, wx = (wave & 1) * 32;

    int srow = (wave << 4) + (lane >> 2);
    int scg = ((lane & 3) ^ ((lane >> 3) & 3)) * 8;
    _Float16* lA0 = &As[0][0] + (wave << 9);
    _Float16* lB0 = &Bs[0][0] + (wave << 9);
    int cra = (quad ^ ((l16 >> 1) & 3)) * 8;

    floatx4 acc[4][2] = {};

    for (int k0 = kbeg; k0 < kend; k0 += 32) {
        if (k0 != kbeg) __syncthreads();
        const _Float16* gA = A + (long long)(m0 + srow) * lda + k0 + scg;
        const _Float16* gB = Bt + (long long)(n0 + srow) * ldb + k0 + scg;
#pragma unroll
        for (int j = 0; j < 2; j++)
            __builtin_amdgcn_global_load_lds((gas_ptr)(gA + (long long)(j << 6) * lda),
                                             (las_ptr)(lA0 + (j << 11)), 16, 0, 0);
        __builtin_amdgcn_global_load_lds((gas_ptr)gB, (las_ptr)lB0, 16, 0, 0);
        __syncthreads();

        half8_t af[4], bf[2];
#pragma unroll
        for (int i = 0; i < 4; i++)
            af[i] = *(const half8_t*)&As[wy + i * 16 + l16][cra];
#pragma unroll
        for (int i = 0; i < 2; i++)
            bf[i] = *(const half8_t*)&Bs[wx + i * 16 + l16][cra];
#pragma unroll
        for (int mi = 0; mi < 4; mi++)
#pragma unroll
            for (int ni = 0; ni < 2; ni++)
                acc[mi][ni] = __builtin_amdgcn_mfma_f32_16x16x32_f16(af[mi], bf[ni], acc[mi][ni], 0, 0, 0);
    }

    int addb = (blockIdx.z == 0) && bias;
#pragma unroll
    for (int mi = 0; mi < 4; mi++)
#pragma unroll
        for (int ni = 0; ni < 2; ni++)
#pragma unroll
            for (int r = 0; r < 4; r++) {
                int row = m0 + wy + mi * 16 + quad * 4 + r;
                int col = n0 + wx + ni * 16 + l16;
                float v = acc[mi][ni][r];
                if (addb) v += bias[col];
                atomicAdd(&C[(long long)row * ldc + col], v);
            }
}

extern "C" void kernel_launch(void* const* d_in, const int* in_sizes, int n_in,
                              void* d_out, int out_size, void* d_ws, size_t ws_size,
                              hipStream_t stream)
{
    const float* qin = (const float*)d_in[0];
    const float* kin = (const float*)d_in[1];
    const float* vin = (const float*)d_in[2];
    const int*   mask = (const int*)d_in[3];
    const float* Wq = (const float*)d_in[4];
    const float* bq = (const float*)d_in[5];
    const float* Wk = (const float*)d_in[6];
    const float* bk = (const float*)d_in[7];
    const float* Wv = (const float*)d_in[8];
    const float* bv = (const float*)d_in[9];
    const float* Wo = (const float*)d_in[10];
    const float* bo = (const float*)d_in[11];
    float* out = (float*)d_out;

    char* ws = (char*)d_ws;
    size_t off = 0;
    _Float16* WoT = (_Float16*)(ws + off); off += (size_t)E_ * HE_ * 2;           // 4 MiB
    _Float16* Qb  = (_Float16*)(ws + off); off += (size_t)B_ * H_ * S_ * E_ * 2;  // 32 MiB
    _Float16* Kb  = (_Float16*)(ws + off); off += (size_t)B_ * H_ * S_ * E_ * 2;  // 32 MiB
    _Float16* VT  = (_Float16*)(ws + off); off += (size_t)B_ * H_ * E_ * S_ * 2;  // 32 MiB
    size_t region = off;
    _Float16* Xq  = (_Float16*)(ws + region);
    _Float16* Xk  = Xq  + (size_t)B_ * S_ * D_;
    _Float16* Xv  = Xk  + (size_t)B_ * S_ * D_;
    _Float16* WqT = Xv  + (size_t)B_ * S_ * D_;
    _Float16* WkT = WqT + (size_t)H_ * E_ * D_;
    _Float16* WvT = WkT + (size_t)H_ * E_ * D_;
    _Float16* SC  = (_Float16*)(ws + region);   // fp16 scores -> P (overlays dead scratch)
    _Float16* cat = Qb;                          // aliases Q (dead after scores GEMM)

    long long SE = (long long)S_ * E_;
    long long SS = (long long)S_ * S_;
    long long ES = (long long)E_ * S_;

    // zero d_out (split-K atomic accumulation target)
    (void)hipMemsetAsync(d_out, 0, (size_t)out_size * sizeof(float), stream);

    // 1) cast q,k,v to fp16
    int n4 = B_ * S_ * D_ / 4;
    cast3_f16_kernel<<<dim3(n4 / 256, 3), 256, 0, stream>>>(qin, kin, vin, Xq, Xk, Xv, n4);

    // 2) transpose+cast weights to Bt form
    dim3 tb(32, 8);
    transpose3_cast_kernel<<<dim3(E_ / 32, D_ / 32, 24), tb, 0, stream>>>(
        Wq, Wk, Wv, WqT, WkT, WvT, D_, E_);
    transpose_cast_kernel<<<dim3(E_ / 32, HE_ / 32, 1), tb, 0, stream>>>(Wo, WoT, HE_, E_);

    // 3) merged QKV projections on the phased 256^2 core (48 z-slices, XCD-swizzled)
    gemm_qkv256_kernel<<<dim3(E_ / 256, S_ / 256, 48), 512, 0, stream>>>(
        Xq, Xk, Xv, WqT, WkT, WvT, bq, bk, bv, Qb, Kb, VT);

    // 4a) raw scores [z][s][t]
    gemm_bt256_kernel<<<dim3(S_ / 256, S_ / 256, B_ * H_), 512, 0, stream>>>(
        Qb, Kb, SC, E_, E_, E_, SE, SE, 0, SS, S_, 32 /*hdiv>z: bb=0,hh=z*/);

    // 4b) masked softmax in place, 8 heads per block
    softmax_mask8_kernel<<<dim3(S_, 1, B_), 512, 0, stream>>>(SC, mask);

    // 4c) P @ V -> cat[b][s][h*E+e]
    gemm_bt256_kernel<<<dim3(E_ / 256, S_ / 256, B_ * H_), 512, 0, stream>>>(
        SC, VT, cat, S_, S_, S_, SS, ES, (long long)S_ * HE_, E_, HE_, H_);

    // 5) output projection: split-K (4) swizzled, atomic fp32 accumulate
    gemm_bt_n64_splitk_kernel<<<dim3(E_ / 64, (B_ * S_) / 128, 4), 256, 0, stream>>>(
        cat, WoT, bo, out, HE_, HE_, HE_, E_, 4);
}